// Round 10
// baseline (694.277 us; speedup 1.0000x reference)
//
#include <hip/hip_runtime.h>
#include <hip/hip_fp16.h>

#define H 256
#define W 256
#define BS 8
#define IC 16          // in_ch (flow fields per batch; also out channels)
#define OCH 32         // conv output channels = 2*IC
#define NSTEPS 7
#define PLANE (H*W)            // 65536
#define NFIELDS (BS*IC)        // 128
#define BN_N (BS*PLANE)        // 524288
#define BN_EPS 1e-5f
// padded plane: interior (y,x) at (y+1, x+1), pitch 260, rows 0..258 used
#define PW 260
#define PSZ (260 * 260)

// ---------------------------------------------------------------------------
// K0: vec_w [oc][ic][3][3] -> wTh [(ic*9+k)][p] as half2 pairs (oc 2p, 2p+1)
// ---------------------------------------------------------------------------
__global__ void transpose_w_kernel(const float* __restrict__ w,
                                   __half2* __restrict__ wTh) {
    for (int idx = threadIdx.x; idx < IC * 9 * 16; idx += blockDim.x) {
        int rc = idx >> 4;        // ic*9+k
        int p  = idx & 15;
        float lo = w[(2 * p) * (IC * 9) + rc];
        float hi = w[(2 * p + 1) * (IC * 9) + rc];
        wTh[idx] = __floats2half2_rn(lo, hi);
    }
}

// ---------------------------------------------------------------------------
// K1: zero the guard borders of the two padded step buffers + padded f16.
// ---------------------------------------------------------------------------
__global__ void guard_zero_kernel(unsigned* __restrict__ bufA,
                                  unsigned* __restrict__ bufB,
                                  unsigned short* __restrict__ f16p) {
    int p = blockIdx.x;           // 128 planes
    size_t pb = (size_t)p * PSZ;
    for (int i = threadIdx.x; i < 2064; i += blockDim.x) {
        int row, col;
        if (i < 1040) {
            int r = i / 260;
            row = (r == 0) ? 0 : 256 + r;     // 0,257,258,259
            col = i - r * 260;
        } else {
            int j = i - 1040;
            int c = j / 256;
            col = (c == 0) ? 0 : 256 + c;     // 0,257,258,259
            row = 1 + (j - c * 256);
        }
        size_t off = pb + (size_t)row * PW + col;
        bufA[off] = 0u;
        bufB[off] = 0u;
        f16p[off] = 0;
    }
}

// ---------------------------------------------------------------------------
// K1b: build padded f16 copy of f (interior cells; guards zeroed by K1).
// ---------------------------------------------------------------------------
__global__ __launch_bounds__(256) void dup_kernel(const float* __restrict__ f,
                                                  __half* __restrict__ f16p) {
    int blk = blockIdx.x;            // NFIELDS*8 = 1024 blocks, 32 rows each
    int p  = blk >> 3;
    int r0 = (blk & 7) * 32;
    const float* fp = f + (size_t)p * PLANE;
    __half* dp = f16p + (size_t)p * PSZ;
    int tx = threadIdx.x;
#pragma unroll 4
    for (int ry = 0; ry < 32; ++ry) {
        int y = r0 + ry;
        dp[(size_t)(y + 1) * PW + tx + 1] = __float2half(fp[(size_t)y * W + tx]);
    }
}

// ---------------------------------------------------------------------------
// K2: 3x3 conv (16->32) + bias in PACKED FP16. (R4 structure, measured:
// ~57us; 32 waves/CU = HW max — leave alone.)
// ---------------------------------------------------------------------------
__global__ __launch_bounds__(256, 8) void conv_kernel(
    const float* __restrict__ f, const __half2* __restrict__ wTh,
    const float* __restrict__ vec_b, __half2* __restrict__ vec_out) {
    __shared__ __align__(16) __half sf[16][10][40];   // 12.5 KB

    int blk = blockIdx.x;              // 2048
    int xcd = blk & 7;
    int i   = blk >> 3;
    int b   = i >> 5;
    int j   = i & 31;
    int ty0 = ((xcd << 2) | (j >> 3)) * 8;   // 32 row-bands of 8
    int tx0 = (j & 7) * 32;
    int tid = threadIdx.x;

    {
        int sic = tid >> 4;
        int st  = tid & 15;
        if (st < 10) {
            int gx0 = tx0 - 4 + 4 * st;
            const float* fpl = f + (size_t)(b * IC + sic) * PLANE;
            bool full = (gx0 >= 0) && (gx0 + 3 < W);
#pragma unroll
            for (int r = 0; r < 10; ++r) {
                int gy = ty0 - 1 + r;
                float4 v = make_float4(0.f, 0.f, 0.f, 0.f);
                if ((unsigned)gy < (unsigned)H) {
                    if (full) {
                        v = *(const float4*)(fpl + (size_t)gy * W + gx0);
                    } else {
                        if ((unsigned)(gx0 + 0) < (unsigned)W) v.x = fpl[(size_t)gy * W + gx0 + 0];
                        if ((unsigned)(gx0 + 1) < (unsigned)W) v.y = fpl[(size_t)gy * W + gx0 + 1];
                        if ((unsigned)(gx0 + 2) < (unsigned)W) v.z = fpl[(size_t)gy * W + gx0 + 2];
                        if ((unsigned)(gx0 + 3) < (unsigned)W) v.w = fpl[(size_t)gy * W + gx0 + 3];
                    }
                }
                union { __half2 h[2]; float2 f2; } u;
                u.h[0] = __floats2half2_rn(v.x, v.y);
                u.h[1] = __floats2half2_rn(v.z, v.w);
                *(float2*)&sf[sic][r][4 * st] = u.f2;
            }
        }
    }

    __half2 acc[16];
#pragma unroll
    for (int p = 0; p < 16; ++p)
        acc[p] = __floats2half2_rn(vec_b[2 * p], vec_b[2 * p + 1]);

    __syncthreads();

    int tyl = tid >> 5, txl = tid & 31;
#pragma unroll 2
    for (int ic = 0; ic < 16; ++ic) {
#pragma unroll
        for (int k = 0; k < 9; ++k) {
            int ky = k / 3, kx = k - ky * 3;
            __half2 fv = __half2half2(sf[ic][tyl + ky][txl + kx + 3]);
            const __half2* wrow = wTh + (ic * 9 + k) * 16;   // wave-uniform -> s_load
#pragma unroll
            for (int p = 0; p < 16; ++p)
                acc[p] = __hfma2(fv, wrow[p], acc[p]);
        }
    }

    int y = ty0 + tyl, x = tx0 + txl;
#pragma unroll
    for (int c = 0; c < IC; ++c)
        vec_out[(size_t)(b * IC + c) * PLANE + (size_t)y * W + x] = acc[c];
}

// ---------------------------------------------------------------------------
// K3: per-channel sum / sumsq over the half2 conv output (unpadded).
// ---------------------------------------------------------------------------
__global__ __launch_bounds__(256) void stats_kernel(
    const __half2* __restrict__ vec, float* __restrict__ stats) {
    int blk   = blockIdx.x;            // 2048
    int n     = blk >> 4;
    int chunk = blk & 15;
    const float4* p4 = (const float4*)(vec + (size_t)n * PLANE + chunk * 4096);
    int tid = threadIdx.x;

    float s0 = 0.f, s1 = 0.f, q0 = 0.f, q1 = 0.f;
#pragma unroll 2
    for (int i = tid; i < 1024; i += 256) {
        float4 w = p4[i];
        const __half2* hh = (const __half2*)&w;
#pragma unroll
        for (int q = 0; q < 4; ++q) {
            float2 v = __half22float2(hh[q]);
            s0 += v.x; s1 += v.y;
            q0 = fmaf(v.x, v.x, q0);
            q1 = fmaf(v.y, v.y, q1);
        }
    }
#pragma unroll
    for (int off = 32; off > 0; off >>= 1) {
        s0 += __shfl_down(s0, off, 64);
        s1 += __shfl_down(s1, off, 64);
        q0 += __shfl_down(q0, off, 64);
        q1 += __shfl_down(q1, off, 64);
    }
    __shared__ float red[4][4];
    int wave = tid >> 6, lane = tid & 63;
    if (lane == 0) {
        red[wave][0] = s0; red[wave][1] = s1;
        red[wave][2] = q0; red[wave][3] = q1;
    }
    __syncthreads();
    if (tid == 0) {
        float t0 = 0.f, t1 = 0.f, t2 = 0.f, t3 = 0.f;
#pragma unroll
        for (int wv = 0; wv < 4; ++wv) {
            t0 += red[wv][0]; t1 += red[wv][1];
            t2 += red[wv][2]; t3 += red[wv][3];
        }
        int ch0 = 2 * (n & 15);
        atomicAdd(stats + ch0,          t0);
        atomicAdd(stats + ch0 + 1,      t1);
        atomicAdd(stats + 32 + ch0,     t2);
        atomicAdd(stats + 32 + ch0 + 1, t3);
    }
}

// ---------------------------------------------------------------------------
// K4: fold BN + 1/128 scale into per-channel affine.
// ---------------------------------------------------------------------------
__global__ void finalize_kernel(const float* __restrict__ stats,
                                const float* __restrict__ gamma,
                                const float* __restrict__ beta,
                                float* __restrict__ AB) {
    int ch = threadIdx.x;
    if (ch < 2 * IC) {
        const float invN = 1.f / (float)BN_N;
        float mean = stats[ch] * invN;
        float var  = stats[32 + ch] * invN - mean * mean;
        float rs   = rsqrtf(var + BN_EPS);
        float a    = gamma[ch] * rs;
        AB[ch]      = a * (1.f / 128.f);
        AB[32 + ch] = (beta[ch] - a * mean) * (1.f / 128.f);
    }
}

// ---------------------------------------------------------------------------
// masked tap setup (unpadded planes; FIRST-step deform reads only)
// ---------------------------------------------------------------------------
__device__ __forceinline__ void tap_setup(float py, float px,
                                          int* o, float* wt) {
    float ffy = floorf(py), ffx = floorf(px);
    int y0 = (int)ffy, x0 = (int)ffx;
    float wy1 = py - ffy, wy0 = 1.f - wy1;
    float wx1 = px - ffx, wx0 = 1.f - wx1;
    bool vy0 = (unsigned)y0 < (unsigned)H, vy1 = (unsigned)(y0 + 1) < (unsigned)H;
    bool vx0 = (unsigned)x0 < (unsigned)W, vx1 = (unsigned)(x0 + 1) < (unsigned)W;
    int yc0 = min(max(y0, 0), H - 1), yc1 = min(max(y0 + 1, 0), H - 1);
    int xc0 = min(max(x0, 0), W - 1), xc1 = min(max(x0 + 1, 0), W - 1);
    o[0] = yc0 * W + xc0; o[1] = yc0 * W + xc1;
    o[2] = yc1 * W + xc0; o[3] = yc1 * W + xc1;
    wt[0] = (vy0 && vx0) ? wy0 * wx0 : 0.f;
    wt[1] = (vy0 && vx1) ? wy0 * wx1 : 0.f;
    wt[2] = (vy1 && vx0) ? wy1 * wx0 : 0.f;
    wt[3] = (vy1 && vx1) ? wy1 * wx1 : 0.f;
}

// ---------------------------------------------------------------------------
// fast tap setup for guard-padded planes
// ---------------------------------------------------------------------------
__device__ __forceinline__ void tap_fast(float py, float px,
                                         int& o, float* wt) {
    float pyc = fminf(fmaxf(py, -1.f), 256.f);
    float pxc = fminf(fmaxf(px, -1.f), 256.f);
    float fy = floorf(pyc), fx = floorf(pxc);
    int y0 = (int)fy, x0 = (int)fx;
    float wy1 = pyc - fy, wy0 = 1.f - wy1;
    float wx1 = pxc - fx, wx0 = 1.f - wx1;
    o = (y0 + 1) * PW + (x0 + 1);
    wt[0] = wy0 * wx0; wt[1] = wy0 * wx1;
    wt[2] = wy1 * wx0; wt[3] = wy1 * wx1;
}

// ---------------------------------------------------------------------------
// K5 (R10): channel-split warp step, batch-half version (64 fields/half).
// Block = (field, 8-row band): gather set ~19 KB -> L1 (measured R9:
// 46us full-width vs 57.6 fused). f0 = first field of the half.
// ---------------------------------------------------------------------------
template <bool FIRST, bool LAST>
__global__ __launch_bounds__(256, 4) void warp_step(
    const __half2* __restrict__ vinRaw, const __half2* __restrict__ vinPad,
    __half2* __restrict__ voutPad, const __half* __restrict__ f16p,
    const float* __restrict__ AB, __half* __restrict__ mvOut, int f0) {
    int blk  = blockIdx.x;            // 2048 = 64 fields x 32 bands
    int fldl = blk & 63;
    int band = blk >> 6;
    int fld  = f0 + fldl;
    int c    = fld & 15;
    int tx   = threadIdx.x;
    const __half2* vinR = FIRST ? vinRaw + (size_t)fld * PLANE : nullptr;
    const __half2* vinP = FIRST ? nullptr : vinPad + (size_t)fld * PSZ;
    __half2* voutP = LAST ? nullptr : voutPad + (size_t)fld * PSZ;
    const __half* fp = f16p + (size_t)fld * PSZ;
    __half* mv = mvOut + (size_t)fldl * PLANE;

    float a0 = 0.f, b0 = 0.f, a1 = 0.f, b1 = 0.f;
    if (FIRST) {
        a0 = AB[2 * c];     b0 = AB[32 + 2 * c];
        a1 = AB[2 * c + 1]; b1 = AB[32 + 2 * c + 1];
    }

#pragma unroll 4
    for (int r = 0; r < 8; ++r) {
        int h = band * 8 + r;
        int idx_raw = h * W + tx;
        int idx_pad = (h + 1) * PW + tx + 1;
        float ny, nx;
        if (FIRST) {
            float2 vc = __half22float2(vinR[idx_raw]);
            float fy = fmaf(a0, vc.x, b0);
            float fx = fmaf(a1, vc.y, b1);
            int om[4]; float wt[4];
            tap_setup((float)h + fy, (float)tx + fx, om, wt);
            float2 t0 = __half22float2(vinR[om[0]]);
            float2 t1 = __half22float2(vinR[om[1]]);
            float2 t2 = __half22float2(vinR[om[2]]);
            float2 t3 = __half22float2(vinR[om[3]]);
            float Sy = wt[0] * t0.x + wt[1] * t1.x + wt[2] * t2.x + wt[3] * t3.x;
            float Sx = wt[0] * t0.y + wt[1] * t1.y + wt[2] * t2.y + wt[3] * t3.y;
            float Ws = wt[0] + wt[1] + wt[2] + wt[3];
            ny = fy + fmaf(a0, Sy, b0 * Ws);
            nx = fx + fmaf(a1, Sx, b1 * Ws);
        } else {
            float2 vc = __half22float2(vinP[idx_pad]);
            float fy = vc.x, fx = vc.y;
            int ob; float wt[4];
            tap_fast((float)h + fy, (float)tx + fx, ob, wt);
            union { float2 f2; __half2 hh[2]; } top, bot;
            top.f2 = *reinterpret_cast<const float2*>(vinP + ob);
            bot.f2 = *reinterpret_cast<const float2*>(vinP + ob + PW);
            float2 t0 = __half22float2(top.hh[0]);
            float2 t1 = __half22float2(top.hh[1]);
            float2 t2 = __half22float2(bot.hh[0]);
            float2 t3 = __half22float2(bot.hh[1]);
            ny = fy + wt[0] * t0.x + wt[1] * t1.x + wt[2] * t2.x + wt[3] * t3.x;
            nx = fx + wt[0] * t0.y + wt[1] * t1.y + wt[2] * t2.y + wt[3] * t3.y;
        }
        if (!LAST)
            voutP[idx_pad] = __float22half2_rn(make_float2(ny, nx));
        int pb; float pw[4];
        tap_fast((float)h + ny, (float)tx + nx, pb, pw);
        union { float f; __half2 h2; } r0u, r1u;
        r0u.f = *reinterpret_cast<const float*>(fp + pb);
        r1u.f = *reinterpret_cast<const float*>(fp + pb + PW);
        float2 g0 = __half22float2(r0u.h2);
        float2 g1 = __half22float2(r1u.h2);
        float m = pw[0] * g0.x + pw[1] * g0.y + pw[2] * g1.x + pw[3] * g1.y;
        mv[idx_raw] = __float2half(m);
    }
}

// ---------------------------------------------------------------------------
// K6 (R10): deferred fuse mix, batch-half, latency-fixed.
// R9's 163us pathology: load m[c] -> 16 FMA -> waitcnt per load (112 serial
// ~500cyc loads). Fix: batched m2[16] preload per step, THEN the FMA block;
// 2 px/thread via half2 loads. fp32 acc, float2 stores.
// ---------------------------------------------------------------------------
__global__ __launch_bounds__(256) void mix_kernel(
    const __half* __restrict__ mvs,   // [6][64][PLANE] (per-half region)
    const __half* __restrict__ mv6,   // bufRaw + f0*PLANE alias
    const float* __restrict__ fw, const float* __restrict__ fb,
    float* __restrict__ out, int b0) {
    int blk = blockIdx.x;             // 512 = 4 bl x 128 hpair
    int bl  = blk >> 7;
    int hp  = blk & 127;
    int tid = threadIdx.x;
    int h   = hp * 2 + (tid >> 7);
    int px  = (tid & 127) << 1;
    int idx = h * W + px;

    float ax[IC], ay[IC];
#pragma unroll
    for (int o = 0; o < IC; ++o) { ax[o] = fb[o]; ay[o] = fb[o]; }

#pragma unroll
    for (int s = 0; s < NSTEPS; ++s) {
        const __half* base = (s < NSTEPS - 1)
            ? mvs + ((size_t)s * 64 + (size_t)bl * IC) * PLANE
            : mv6 + (size_t)bl * IC * PLANE;
        __half2 m2[IC];
#pragma unroll
        for (int c = 0; c < IC; ++c)
            m2[c] = *reinterpret_cast<const __half2*>(base + (size_t)c * PLANE + idx);
#pragma unroll
        for (int c = 0; c < IC; ++c) {
            float2 m = __half22float2(m2[c]);
#pragma unroll
            for (int o = 0; o < IC; ++o) {
                float w = fw[(o * IC + c) * NSTEPS + s];
                ax[o] = fmaf(w, m.x, ax[o]);
                ay[o] = fmaf(w, m.y, ay[o]);
            }
        }
    }

    int b = b0 + bl;
#pragma unroll
    for (int o = 0; o < IC; ++o)
        *reinterpret_cast<float2*>(out + (size_t)(b * IC + o) * PLANE + idx)
            = make_float2(ax[o], ay[o]);
}

// ---------------------------------------------------------------------------
extern "C" void kernel_launch(void* const* d_in, const int* in_sizes, int n_in,
                              void* d_out, int out_size, void* d_ws,
                              size_t ws_size, hipStream_t stream) {
    const float* f      = (const float*)d_in[0];
    const float* vec_w  = (const float*)d_in[1];
    const float* vec_b  = (const float*)d_in[2];
    const float* gamma  = (const float*)d_in[3];
    const float* beta   = (const float*)d_in[4];
    const float* fuse_w = (const float*)d_in[5];
    const float* fuse_b = (const float*)d_in[6];
    float* out = (float*)d_out;

    // ws layout (bytes):
    //   bufRaw: 33.55 MB (conv out; per-half mv6 alias after that half's s=0)
    //   bufA: 34.61  bufB: 34.61  f16p: 17.31
    //   small: 16 KB (wTh, stats, AB)
    //   mvs: 6 x 64 x PLANE half = 50.33 MB (REUSED across the two halves)
    //   total ~170.4 MB (R9 proved ws >= 220 MB)
    char* ws = (char*)d_ws;
    const size_t rawB   = (size_t)NFIELDS * PLANE * sizeof(__half2);
    const size_t padB2  = (size_t)NFIELDS * PSZ * sizeof(__half2);
    const size_t padB1  = (size_t)NFIELDS * PSZ * sizeof(__half);
    const size_t smallB = 16384;
    __half2* bufRaw = (__half2*)ws;
    __half2* bufA   = (__half2*)(ws + rawB);
    __half2* bufB   = (__half2*)(ws + rawB + padB2);
    __half*  f16p   = (__half*)(ws + rawB + 2 * padB2);
    char*    smallp = ws + rawB + 2 * padB2 + padB1;
    __half2* wTh    = (__half2*)smallp;                       // 9216 B
    float*   stats  = (float*)(smallp + 10240);               // 256 B
    float*   AB     = (float*)(smallp + 10240 + 256);         // 256 B
    __half*  mvs    = (__half*)(smallp + smallB);

    hipMemsetAsync(stats, 0, 64 * sizeof(float), stream);
    transpose_w_kernel<<<1, 512, 0, stream>>>(vec_w, wTh);
    guard_zero_kernel<<<NFIELDS, 256, 0, stream>>>(
        (unsigned*)bufA, (unsigned*)bufB, (unsigned short*)f16p);
    dup_kernel<<<NFIELDS * 8, 256, 0, stream>>>(f, f16p);
    conv_kernel<<<2048, 256, 0, stream>>>(f, wTh, vec_b, bufRaw);
    stats_kernel<<<NFIELDS * 16, 256, 0, stream>>>(bufRaw, stats);
    finalize_kernel<<<1, 64, 0, stream>>>(stats, gamma, beta, AB);

    const size_t mvHalf = (size_t)64 * PLANE;   // halfs per step-buffer slot
    for (int hf = 0; hf < 2; ++hf) {
        int f0 = hf * 64;
        for (int s = 0; s < NSTEPS; ++s) {
            const __half2* vinPad = (s & 1) ? bufA : bufB;
            __half2*       voutP  = (s & 1) ? bufB : bufA;
            __half* mvP = (s < NSTEPS - 1)
                ? mvs + (size_t)s * mvHalf
                : (__half*)bufRaw + (size_t)f0 * PLANE;  // alias, safe after s=0
            if (s == 0)
                warp_step<true, false><<<2048, 256, 0, stream>>>(
                    bufRaw, (const __half2*)nullptr, bufA, f16p, AB, mvP, f0);
            else if (s < NSTEPS - 1)
                warp_step<false, false><<<2048, 256, 0, stream>>>(
                    (const __half2*)nullptr, vinPad, voutP, f16p, AB, mvP, f0);
            else
                warp_step<false, true><<<2048, 256, 0, stream>>>(
                    (const __half2*)nullptr, vinPad, (__half2*)nullptr, f16p,
                    AB, mvP, f0);
        }
        mix_kernel<<<512, 256, 0, stream>>>(
            mvs, (const __half*)bufRaw + (size_t)f0 * PLANE,
            fuse_w, fuse_b, out, f0 >> 4);
    }
}

// Round 11
// 498.232 us; speedup vs baseline: 1.3935x; 1.3935x over previous
//
#include <hip/hip_runtime.h>
#include <hip/hip_fp16.h>

#define H 256
#define W 256
#define BS 8
#define IC 16          // in_ch (flow fields per batch; also out channels)
#define OCH 32         // conv output channels = 2*IC
#define NSTEPS 7
#define PLANE (H*W)            // 65536
#define NFIELDS (BS*IC)        // 128
#define BN_N (BS*PLANE)        // 524288
#define BN_EPS 1e-5f
// padded plane: interior (y,x) at (y+1, x+1), pitch 260, rows 0..258 used
#define PW 260
#define PSZ (260 * 260)

// ---------------------------------------------------------------------------
// K0: vec_w [oc][ic][3][3] -> wTh [(ic*9+k)][p] as half2 pairs (oc 2p, 2p+1)
// ---------------------------------------------------------------------------
__global__ void transpose_w_kernel(const float* __restrict__ w,
                                   __half2* __restrict__ wTh) {
    for (int idx = threadIdx.x; idx < IC * 9 * 16; idx += blockDim.x) {
        int rc = idx >> 4;        // ic*9+k
        int p  = idx & 15;
        float lo = w[(2 * p) * (IC * 9) + rc];
        float hi = w[(2 * p + 1) * (IC * 9) + rc];
        wTh[idx] = __floats2half2_rn(lo, hi);
    }
}

// ---------------------------------------------------------------------------
// K1: zero the guard borders of the two padded step buffers + padded f16.
// ---------------------------------------------------------------------------
__global__ void guard_zero_kernel(unsigned* __restrict__ bufA,
                                  unsigned* __restrict__ bufB,
                                  unsigned short* __restrict__ f16p) {
    int p = blockIdx.x;           // 128 planes
    size_t pb = (size_t)p * PSZ;
    for (int i = threadIdx.x; i < 2064; i += blockDim.x) {
        int row, col;
        if (i < 1040) {
            int r = i / 260;
            row = (r == 0) ? 0 : 256 + r;     // 0,257,258,259
            col = i - r * 260;
        } else {
            int j = i - 1040;
            int c = j / 256;
            col = (c == 0) ? 0 : 256 + c;     // 0,257,258,259
            row = 1 + (j - c * 256);
        }
        size_t off = pb + (size_t)row * PW + col;
        bufA[off] = 0u;
        bufB[off] = 0u;
        f16p[off] = 0;
    }
}

// ---------------------------------------------------------------------------
// K1b: build padded f16 copy of f (interior cells; guards zeroed by K1).
// ---------------------------------------------------------------------------
__global__ __launch_bounds__(256) void dup_kernel(const float* __restrict__ f,
                                                  __half* __restrict__ f16p) {
    int blk = blockIdx.x;            // NFIELDS*8 = 1024 blocks, 32 rows each
    int p  = blk >> 3;
    int r0 = (blk & 7) * 32;
    const float* fp = f + (size_t)p * PLANE;
    __half* dp = f16p + (size_t)p * PSZ;
    int tx = threadIdx.x;
#pragma unroll 4
    for (int ry = 0; ry < 32; ++ry) {
        int y = r0 + ry;
        dp[(size_t)(y + 1) * PW + tx + 1] = __float2half(fp[(size_t)y * W + tx]);
    }
}

// ---------------------------------------------------------------------------
// K2: 3x3 conv (16->32) + bias in PACKED FP16. (R4 structure, measured:
// ~57us; 32 waves/CU = HW max — leave alone.)
// ---------------------------------------------------------------------------
__global__ __launch_bounds__(256, 8) void conv_kernel(
    const float* __restrict__ f, const __half2* __restrict__ wTh,
    const float* __restrict__ vec_b, __half2* __restrict__ vec_out) {
    __shared__ __align__(16) __half sf[16][10][40];   // 12.5 KB

    int blk = blockIdx.x;              // 2048
    int xcd = blk & 7;
    int i   = blk >> 3;
    int b   = i >> 5;
    int j   = i & 31;
    int ty0 = ((xcd << 2) | (j >> 3)) * 8;   // 32 row-bands of 8
    int tx0 = (j & 7) * 32;
    int tid = threadIdx.x;

    {
        int sic = tid >> 4;
        int st  = tid & 15;
        if (st < 10) {
            int gx0 = tx0 - 4 + 4 * st;
            const float* fpl = f + (size_t)(b * IC + sic) * PLANE;
            bool full = (gx0 >= 0) && (gx0 + 3 < W);
#pragma unroll
            for (int r = 0; r < 10; ++r) {
                int gy = ty0 - 1 + r;
                float4 v = make_float4(0.f, 0.f, 0.f, 0.f);
                if ((unsigned)gy < (unsigned)H) {
                    if (full) {
                        v = *(const float4*)(fpl + (size_t)gy * W + gx0);
                    } else {
                        if ((unsigned)(gx0 + 0) < (unsigned)W) v.x = fpl[(size_t)gy * W + gx0 + 0];
                        if ((unsigned)(gx0 + 1) < (unsigned)W) v.y = fpl[(size_t)gy * W + gx0 + 1];
                        if ((unsigned)(gx0 + 2) < (unsigned)W) v.z = fpl[(size_t)gy * W + gx0 + 2];
                        if ((unsigned)(gx0 + 3) < (unsigned)W) v.w = fpl[(size_t)gy * W + gx0 + 3];
                    }
                }
                union { __half2 h[2]; float2 f2; } u;
                u.h[0] = __floats2half2_rn(v.x, v.y);
                u.h[1] = __floats2half2_rn(v.z, v.w);
                *(float2*)&sf[sic][r][4 * st] = u.f2;
            }
        }
    }

    __half2 acc[16];
#pragma unroll
    for (int p = 0; p < 16; ++p)
        acc[p] = __floats2half2_rn(vec_b[2 * p], vec_b[2 * p + 1]);

    __syncthreads();

    int tyl = tid >> 5, txl = tid & 31;
#pragma unroll 2
    for (int ic = 0; ic < 16; ++ic) {
#pragma unroll
        for (int k = 0; k < 9; ++k) {
            int ky = k / 3, kx = k - ky * 3;
            __half2 fv = __half2half2(sf[ic][tyl + ky][txl + kx + 3]);
            const __half2* wrow = wTh + (ic * 9 + k) * 16;   // wave-uniform -> s_load
#pragma unroll
            for (int p = 0; p < 16; ++p)
                acc[p] = __hfma2(fv, wrow[p], acc[p]);
        }
    }

    int y = ty0 + tyl, x = tx0 + txl;
#pragma unroll
    for (int c = 0; c < IC; ++c)
        vec_out[(size_t)(b * IC + c) * PLANE + (size_t)y * W + x] = acc[c];
}

// ---------------------------------------------------------------------------
// K3: per-channel sum / sumsq over the half2 conv output (unpadded).
// ---------------------------------------------------------------------------
__global__ __launch_bounds__(256) void stats_kernel(
    const __half2* __restrict__ vec, float* __restrict__ stats) {
    int blk   = blockIdx.x;            // 2048
    int n     = blk >> 4;
    int chunk = blk & 15;
    const float4* p4 = (const float4*)(vec + (size_t)n * PLANE + chunk * 4096);
    int tid = threadIdx.x;

    float s0 = 0.f, s1 = 0.f, q0 = 0.f, q1 = 0.f;
#pragma unroll 2
    for (int i = tid; i < 1024; i += 256) {
        float4 w = p4[i];
        const __half2* hh = (const __half2*)&w;
#pragma unroll
        for (int q = 0; q < 4; ++q) {
            float2 v = __half22float2(hh[q]);
            s0 += v.x; s1 += v.y;
            q0 = fmaf(v.x, v.x, q0);
            q1 = fmaf(v.y, v.y, q1);
        }
    }
#pragma unroll
    for (int off = 32; off > 0; off >>= 1) {
        s0 += __shfl_down(s0, off, 64);
        s1 += __shfl_down(s1, off, 64);
        q0 += __shfl_down(q0, off, 64);
        q1 += __shfl_down(q1, off, 64);
    }
    __shared__ float red[4][4];
    int wave = tid >> 6, lane = tid & 63;
    if (lane == 0) {
        red[wave][0] = s0; red[wave][1] = s1;
        red[wave][2] = q0; red[wave][3] = q1;
    }
    __syncthreads();
    if (tid == 0) {
        float t0 = 0.f, t1 = 0.f, t2 = 0.f, t3 = 0.f;
#pragma unroll
        for (int wv = 0; wv < 4; ++wv) {
            t0 += red[wv][0]; t1 += red[wv][1];
            t2 += red[wv][2]; t3 += red[wv][3];
        }
        int ch0 = 2 * (n & 15);
        atomicAdd(stats + ch0,          t0);
        atomicAdd(stats + ch0 + 1,      t1);
        atomicAdd(stats + 32 + ch0,     t2);
        atomicAdd(stats + 32 + ch0 + 1, t3);
    }
}

// ---------------------------------------------------------------------------
// K4: fold BN + 1/128 scale into per-channel affine.
// ---------------------------------------------------------------------------
__global__ void finalize_kernel(const float* __restrict__ stats,
                                const float* __restrict__ gamma,
                                const float* __restrict__ beta,
                                float* __restrict__ AB) {
    int ch = threadIdx.x;
    if (ch < 2 * IC) {
        const float invN = 1.f / (float)BN_N;
        float mean = stats[ch] * invN;
        float var  = stats[32 + ch] * invN - mean * mean;
        float rs   = rsqrtf(var + BN_EPS);
        float a    = gamma[ch] * rs;
        AB[ch]      = a * (1.f / 128.f);
        AB[32 + ch] = (beta[ch] - a * mean) * (1.f / 128.f);
    }
}

// ---------------------------------------------------------------------------
// masked tap setup (unpadded planes; FIRST-step deform reads only)
// ---------------------------------------------------------------------------
__device__ __forceinline__ void tap_setup(float py, float px,
                                          int* o, float* wt) {
    float ffy = floorf(py), ffx = floorf(px);
    int y0 = (int)ffy, x0 = (int)ffx;
    float wy1 = py - ffy, wy0 = 1.f - wy1;
    float wx1 = px - ffx, wx0 = 1.f - wx1;
    bool vy0 = (unsigned)y0 < (unsigned)H, vy1 = (unsigned)(y0 + 1) < (unsigned)H;
    bool vx0 = (unsigned)x0 < (unsigned)W, vx1 = (unsigned)(x0 + 1) < (unsigned)W;
    int yc0 = min(max(y0, 0), H - 1), yc1 = min(max(y0 + 1, 0), H - 1);
    int xc0 = min(max(x0, 0), W - 1), xc1 = min(max(x0 + 1, 0), W - 1);
    o[0] = yc0 * W + xc0; o[1] = yc0 * W + xc1;
    o[2] = yc1 * W + xc0; o[3] = yc1 * W + xc1;
    wt[0] = (vy0 && vx0) ? wy0 * wx0 : 0.f;
    wt[1] = (vy0 && vx1) ? wy0 * wx1 : 0.f;
    wt[2] = (vy1 && vx0) ? wy1 * wx0 : 0.f;
    wt[3] = (vy1 && vx1) ? wy1 * wx1 : 0.f;
}

// ---------------------------------------------------------------------------
// fast tap setup for guard-padded planes
// ---------------------------------------------------------------------------
__device__ __forceinline__ void tap_fast(float py, float px,
                                         int& o, float* wt) {
    float pyc = fminf(fmaxf(py, -1.f), 256.f);
    float pxc = fminf(fmaxf(px, -1.f), 256.f);
    float fy = floorf(pyc), fx = floorf(pxc);
    int y0 = (int)fy, x0 = (int)fx;
    float wy1 = pyc - fy, wy0 = 1.f - wy1;
    float wx1 = pxc - fx, wx0 = 1.f - wx1;
    o = (y0 + 1) * PW + (x0 + 1);
    wt[0] = wy0 * wx0; wt[1] = wy0 * wx1;
    wt[2] = wy1 * wx0; wt[3] = wy1 * wx1;
}

// ---------------------------------------------------------------------------
// K5 (R11 = R9 full-width, proven 46us/step): channel-split warp step.
// Block = (field, 8-row band): gather set ~19 KB -> L1-resident.
// ---------------------------------------------------------------------------
template <bool FIRST, bool LAST>
__global__ __launch_bounds__(256, 4) void warp_step(
    const __half2* __restrict__ vinRaw, const __half2* __restrict__ vinPad,
    __half2* __restrict__ voutPad, const __half* __restrict__ f16p,
    const float* __restrict__ AB, __half* __restrict__ mvOut) {
    int blk  = blockIdx.x;            // 4096 = 128 fields x 32 bands
    int fld  = blk & 127;
    int band = blk >> 7;
    int c    = fld & 15;
    int tx   = threadIdx.x;
    const __half2* vinR = FIRST ? vinRaw + (size_t)fld * PLANE : nullptr;
    const __half2* vinP = FIRST ? nullptr : vinPad + (size_t)fld * PSZ;
    __half2* voutP = LAST ? nullptr : voutPad + (size_t)fld * PSZ;
    const __half* fp = f16p + (size_t)fld * PSZ;
    __half* mv = mvOut + (size_t)fld * PLANE;

    float a0 = 0.f, b0 = 0.f, a1 = 0.f, b1 = 0.f;
    if (FIRST) {
        a0 = AB[2 * c];     b0 = AB[32 + 2 * c];
        a1 = AB[2 * c + 1]; b1 = AB[32 + 2 * c + 1];
    }

#pragma unroll 4
    for (int r = 0; r < 8; ++r) {
        int h = band * 8 + r;
        int idx_raw = h * W + tx;
        int idx_pad = (h + 1) * PW + tx + 1;
        float ny, nx;
        if (FIRST) {
            float2 vc = __half22float2(vinR[idx_raw]);
            float fy = fmaf(a0, vc.x, b0);
            float fx = fmaf(a1, vc.y, b1);
            int om[4]; float wt[4];
            tap_setup((float)h + fy, (float)tx + fx, om, wt);
            float2 t0 = __half22float2(vinR[om[0]]);
            float2 t1 = __half22float2(vinR[om[1]]);
            float2 t2 = __half22float2(vinR[om[2]]);
            float2 t3 = __half22float2(vinR[om[3]]);
            float Sy = wt[0] * t0.x + wt[1] * t1.x + wt[2] * t2.x + wt[3] * t3.x;
            float Sx = wt[0] * t0.y + wt[1] * t1.y + wt[2] * t2.y + wt[3] * t3.y;
            float Ws = wt[0] + wt[1] + wt[2] + wt[3];
            ny = fy + fmaf(a0, Sy, b0 * Ws);
            nx = fx + fmaf(a1, Sx, b1 * Ws);
        } else {
            float2 vc = __half22float2(vinP[idx_pad]);
            float fy = vc.x, fx = vc.y;
            int ob; float wt[4];
            tap_fast((float)h + fy, (float)tx + fx, ob, wt);
            union { float2 f2; __half2 hh[2]; } top, bot;
            top.f2 = *reinterpret_cast<const float2*>(vinP + ob);
            bot.f2 = *reinterpret_cast<const float2*>(vinP + ob + PW);
            float2 t0 = __half22float2(top.hh[0]);
            float2 t1 = __half22float2(top.hh[1]);
            float2 t2 = __half22float2(bot.hh[0]);
            float2 t3 = __half22float2(bot.hh[1]);
            ny = fy + wt[0] * t0.x + wt[1] * t1.x + wt[2] * t2.x + wt[3] * t3.x;
            nx = fx + wt[0] * t0.y + wt[1] * t1.y + wt[2] * t2.y + wt[3] * t3.y;
        }
        if (!LAST)
            voutP[idx_pad] = __float22half2_rn(make_float2(ny, nx));
        int pb; float pw[4];
        tap_fast((float)h + ny, (float)tx + nx, pb, pw);
        union { float f; __half2 h2; } r0u, r1u;
        r0u.f = *reinterpret_cast<const float*>(fp + pb);
        r1u.f = *reinterpret_cast<const float*>(fp + pb + PW);
        float2 g0 = __half22float2(r0u.h2);
        float2 g1 = __half22float2(r1u.h2);
        float m = pw[0] * g0.x + pw[1] * g0.y + pw[2] * g1.x + pw[3] * g1.y;
        mv[idx_raw] = __float2half(m);
    }
}

// ---------------------------------------------------------------------------
// K6 (R11): deferred fuse mix v3. Single-variable fix vs R9/R10:
//   - grid 2048 (8 blocks/CU -> high occupancy; R10's 512 = 2/CU was the
//     regression), 1 px/thread (low VGPR)
//   - batched 16-load preload per step (R9's per-load serialization fix)
//   - '#pragma unroll 1' on s: keeps m[] live range to one step (R10's
//     full s-unroll ballooned VGPR to 80)
// fp32 acc; coalesced ushort loads (128B/wave/plane); scalar fw (s_load).
// ---------------------------------------------------------------------------
__global__ __launch_bounds__(256) void mix_kernel(
    const __half* __restrict__ mvs,   // [6][NFIELDS][PLANE]
    const __half* __restrict__ mv6,   // [NFIELDS][PLANE] (bufRaw alias)
    const float* __restrict__ fw, const float* __restrict__ fb,
    float* __restrict__ out) {
    int blk = blockIdx.x;             // 2048 = 8 b x 256 h
    int b   = blk >> 8;
    int h   = blk & 255;
    int tx  = threadIdx.x;
    int idx = h * W + tx;

    float acc[IC];
#pragma unroll
    for (int o = 0; o < IC; ++o) acc[o] = fb[o];

#pragma unroll 1
    for (int s = 0; s < NSTEPS; ++s) {
        const __half* base = (s < NSTEPS - 1)
            ? mvs + (size_t)s * NFIELDS * PLANE : mv6;
        const __half* pbm = base + (size_t)b * IC * PLANE + idx;
        __half m[IC];
#pragma unroll
        for (int c = 0; c < IC; ++c)
            m[c] = pbm[(size_t)c * PLANE];
        const float* fws = fw + s;
#pragma unroll
        for (int c = 0; c < IC; ++c) {
            float mf = __half2float(m[c]);
#pragma unroll
            for (int o = 0; o < IC; ++o)
                acc[o] = fmaf(fws[(o * IC + c) * NSTEPS], mf, acc[o]);
        }
    }

#pragma unroll
    for (int o = 0; o < IC; ++o)
        out[(size_t)(b * IC + o) * PLANE + idx] = acc[o];
}

// ---------------------------------------------------------------------------
extern "C" void kernel_launch(void* const* d_in, const int* in_sizes, int n_in,
                              void* d_out, int out_size, void* d_ws,
                              size_t ws_size, hipStream_t stream) {
    const float* f      = (const float*)d_in[0];
    const float* vec_w  = (const float*)d_in[1];
    const float* vec_b  = (const float*)d_in[2];
    const float* gamma  = (const float*)d_in[3];
    const float* beta   = (const float*)d_in[4];
    const float* fuse_w = (const float*)d_in[5];
    const float* fuse_b = (const float*)d_in[6];
    float* out = (float*)d_out;

    // ws layout (bytes):
    //   bufRaw: 33.55 MB (conv out; mv6 alias after s=0)
    //   bufA: 34.61  bufB: 34.61  f16p: 17.31
    //   small: 16 KB (wTh, stats, AB)
    //   mvs: 6 x NFIELDS x PLANE half = 100.66 MB
    //   total ~220.8 MB (R9 ran this exact footprint)
    char* ws = (char*)d_ws;
    const size_t rawB   = (size_t)NFIELDS * PLANE * sizeof(__half2);
    const size_t padB2  = (size_t)NFIELDS * PSZ * sizeof(__half2);
    const size_t padB1  = (size_t)NFIELDS * PSZ * sizeof(__half);
    const size_t planeH = (size_t)NFIELDS * PLANE * sizeof(__half);
    const size_t smallB = 16384;
    __half2* bufRaw = (__half2*)ws;
    __half2* bufA   = (__half2*)(ws + rawB);
    __half2* bufB   = (__half2*)(ws + rawB + padB2);
    __half*  f16p   = (__half*)(ws + rawB + 2 * padB2);
    char*    smallp = ws + rawB + 2 * padB2 + padB1;
    __half2* wTh    = (__half2*)smallp;                       // 9216 B
    float*   stats  = (float*)(smallp + 10240);               // 256 B
    float*   AB     = (float*)(smallp + 10240 + 256);         // 256 B
    __half*  mvs    = (__half*)(smallp + smallB);

    hipMemsetAsync(stats, 0, 64 * sizeof(float), stream);
    transpose_w_kernel<<<1, 512, 0, stream>>>(vec_w, wTh);
    guard_zero_kernel<<<NFIELDS, 256, 0, stream>>>(
        (unsigned*)bufA, (unsigned*)bufB, (unsigned short*)f16p);
    dup_kernel<<<NFIELDS * 8, 256, 0, stream>>>(f, f16p);
    conv_kernel<<<2048, 256, 0, stream>>>(f, wTh, vec_b, bufRaw);
    stats_kernel<<<NFIELDS * 16, 256, 0, stream>>>(bufRaw, stats);
    finalize_kernel<<<1, 64, 0, stream>>>(stats, gamma, beta, AB);

    // s=0: bufRaw -> bufA; s odd: bufA -> bufB; s even>0: bufB -> bufA
    for (int s = 0; s < NSTEPS; ++s) {
        const __half2* vinPad = (s & 1) ? bufA : bufB;
        __half2*       voutP  = (s & 1) ? bufB : bufA;
        __half* mvP = (s < NSTEPS - 1) ? mvs + (size_t)s * NFIELDS * PLANE
                                       : (__half*)bufRaw;  // alias, safe after s=0
        if (s == 0)
            warp_step<true, false><<<4096, 256, 0, stream>>>(
                bufRaw, (const __half2*)nullptr, bufA, f16p, AB, mvP);
        else if (s < NSTEPS - 1)
            warp_step<false, false><<<4096, 256, 0, stream>>>(
                (const __half2*)nullptr, vinPad, voutP, f16p, AB, mvP);
        else
            warp_step<false, true><<<4096, 256, 0, stream>>>(
                (const __half2*)nullptr, vinPad, (__half2*)nullptr, f16p,
                AB, mvP);
    }
    mix_kernel<<<2048, 256, 0, stream>>>(
        mvs, (const __half*)bufRaw, fuse_w, fuse_b, out);
}

// Round 12
// 469.898 us; speedup vs baseline: 1.4775x; 1.0603x over previous
//
#include <hip/hip_runtime.h>
#include <hip/hip_fp16.h>

#define H 256
#define W 256
#define BS 8
#define IC 16          // in_ch (flow fields per batch; also out channels)
#define OCH 32         // conv output channels = 2*IC
#define NSTEPS 7
#define PLANE (H*W)            // 65536
#define NFIELDS (BS*IC)        // 128
#define BN_N (BS*PLANE)        // 524288
#define BN_EPS 1e-5f
// padded plane: interior (y,x) at (y+1, x+1), pitch 260, rows 0..258 used
#define PW 260
#define PSZ (260 * 260)

// ---------------------------------------------------------------------------
// K0: vec_w [oc][ic][3][3] -> wTh [(ic*9+k)][p] as half2 pairs (oc 2p, 2p+1)
// ---------------------------------------------------------------------------
__global__ void transpose_w_kernel(const float* __restrict__ w,
                                   __half2* __restrict__ wTh) {
    for (int idx = threadIdx.x; idx < IC * 9 * 16; idx += blockDim.x) {
        int rc = idx >> 4;        // ic*9+k
        int p  = idx & 15;
        float lo = w[(2 * p) * (IC * 9) + rc];
        float hi = w[(2 * p + 1) * (IC * 9) + rc];
        wTh[idx] = __floats2half2_rn(lo, hi);
    }
}

// ---------------------------------------------------------------------------
// K1: zero the guard borders of the two padded step buffers + padded f16.
// ---------------------------------------------------------------------------
__global__ void guard_zero_kernel(unsigned* __restrict__ bufA,
                                  unsigned* __restrict__ bufB,
                                  unsigned short* __restrict__ f16p) {
    int p = blockIdx.x;           // 128 planes
    size_t pb = (size_t)p * PSZ;
    for (int i = threadIdx.x; i < 2064; i += blockDim.x) {
        int row, col;
        if (i < 1040) {
            int r = i / 260;
            row = (r == 0) ? 0 : 256 + r;     // 0,257,258,259
            col = i - r * 260;
        } else {
            int j = i - 1040;
            int c = j / 256;
            col = (c == 0) ? 0 : 256 + c;     // 0,257,258,259
            row = 1 + (j - c * 256);
        }
        size_t off = pb + (size_t)row * PW + col;
        bufA[off] = 0u;
        bufB[off] = 0u;
        f16p[off] = 0;
    }
}

// ---------------------------------------------------------------------------
// K1b: build padded f16 copy of f (interior cells; guards zeroed by K1).
// ---------------------------------------------------------------------------
__global__ __launch_bounds__(256) void dup_kernel(const float* __restrict__ f,
                                                  __half* __restrict__ f16p) {
    int blk = blockIdx.x;            // NFIELDS*8 = 1024 blocks, 32 rows each
    int p  = blk >> 3;
    int r0 = (blk & 7) * 32;
    const float* fp = f + (size_t)p * PLANE;
    __half* dp = f16p + (size_t)p * PSZ;
    int tx = threadIdx.x;
#pragma unroll 4
    for (int ry = 0; ry < 32; ++ry) {
        int y = r0 + ry;
        dp[(size_t)(y + 1) * PW + tx + 1] = __float2half(fp[(size_t)y * W + tx]);
    }
}

// ---------------------------------------------------------------------------
// K2: 3x3 conv (16->32) + bias in PACKED FP16. (R4 structure, measured:
// ~57us; 32 waves/CU = HW max — leave alone.)
// ---------------------------------------------------------------------------
__global__ __launch_bounds__(256, 8) void conv_kernel(
    const float* __restrict__ f, const __half2* __restrict__ wTh,
    const float* __restrict__ vec_b, __half2* __restrict__ vec_out) {
    __shared__ __align__(16) __half sf[16][10][40];   // 12.5 KB

    int blk = blockIdx.x;              // 2048
    int xcd = blk & 7;
    int i   = blk >> 3;
    int b   = i >> 5;
    int j   = i & 31;
    int ty0 = ((xcd << 2) | (j >> 3)) * 8;   // 32 row-bands of 8
    int tx0 = (j & 7) * 32;
    int tid = threadIdx.x;

    {
        int sic = tid >> 4;
        int st  = tid & 15;
        if (st < 10) {
            int gx0 = tx0 - 4 + 4 * st;
            const float* fpl = f + (size_t)(b * IC + sic) * PLANE;
            bool full = (gx0 >= 0) && (gx0 + 3 < W);
#pragma unroll
            for (int r = 0; r < 10; ++r) {
                int gy = ty0 - 1 + r;
                float4 v = make_float4(0.f, 0.f, 0.f, 0.f);
                if ((unsigned)gy < (unsigned)H) {
                    if (full) {
                        v = *(const float4*)(fpl + (size_t)gy * W + gx0);
                    } else {
                        if ((unsigned)(gx0 + 0) < (unsigned)W) v.x = fpl[(size_t)gy * W + gx0 + 0];
                        if ((unsigned)(gx0 + 1) < (unsigned)W) v.y = fpl[(size_t)gy * W + gx0 + 1];
                        if ((unsigned)(gx0 + 2) < (unsigned)W) v.z = fpl[(size_t)gy * W + gx0 + 2];
                        if ((unsigned)(gx0 + 3) < (unsigned)W) v.w = fpl[(size_t)gy * W + gx0 + 3];
                    }
                }
                union { __half2 h[2]; float2 f2; } u;
                u.h[0] = __floats2half2_rn(v.x, v.y);
                u.h[1] = __floats2half2_rn(v.z, v.w);
                *(float2*)&sf[sic][r][4 * st] = u.f2;
            }
        }
    }

    __half2 acc[16];
#pragma unroll
    for (int p = 0; p < 16; ++p)
        acc[p] = __floats2half2_rn(vec_b[2 * p], vec_b[2 * p + 1]);

    __syncthreads();

    int tyl = tid >> 5, txl = tid & 31;
#pragma unroll 2
    for (int ic = 0; ic < 16; ++ic) {
#pragma unroll
        for (int k = 0; k < 9; ++k) {
            int ky = k / 3, kx = k - ky * 3;
            __half2 fv = __half2half2(sf[ic][tyl + ky][txl + kx + 3]);
            const __half2* wrow = wTh + (ic * 9 + k) * 16;   // wave-uniform -> s_load
#pragma unroll
            for (int p = 0; p < 16; ++p)
                acc[p] = __hfma2(fv, wrow[p], acc[p]);
        }
    }

    int y = ty0 + tyl, x = tx0 + txl;
#pragma unroll
    for (int c = 0; c < IC; ++c)
        vec_out[(size_t)(b * IC + c) * PLANE + (size_t)y * W + x] = acc[c];
}

// ---------------------------------------------------------------------------
// K3: per-channel sum / sumsq over the half2 conv output (unpadded).
// ---------------------------------------------------------------------------
__global__ __launch_bounds__(256) void stats_kernel(
    const __half2* __restrict__ vec, float* __restrict__ stats) {
    int blk   = blockIdx.x;            // 2048
    int n     = blk >> 4;
    int chunk = blk & 15;
    const float4* p4 = (const float4*)(vec + (size_t)n * PLANE + chunk * 4096);
    int tid = threadIdx.x;

    float s0 = 0.f, s1 = 0.f, q0 = 0.f, q1 = 0.f;
#pragma unroll 2
    for (int i = tid; i < 1024; i += 256) {
        float4 w = p4[i];
        const __half2* hh = (const __half2*)&w;
#pragma unroll
        for (int q = 0; q < 4; ++q) {
            float2 v = __half22float2(hh[q]);
            s0 += v.x; s1 += v.y;
            q0 = fmaf(v.x, v.x, q0);
            q1 = fmaf(v.y, v.y, q1);
        }
    }
#pragma unroll
    for (int off = 32; off > 0; off >>= 1) {
        s0 += __shfl_down(s0, off, 64);
        s1 += __shfl_down(s1, off, 64);
        q0 += __shfl_down(q0, off, 64);
        q1 += __shfl_down(q1, off, 64);
    }
    __shared__ float red[4][4];
    int wave = tid >> 6, lane = tid & 63;
    if (lane == 0) {
        red[wave][0] = s0; red[wave][1] = s1;
        red[wave][2] = q0; red[wave][3] = q1;
    }
    __syncthreads();
    if (tid == 0) {
        float t0 = 0.f, t1 = 0.f, t2 = 0.f, t3 = 0.f;
#pragma unroll
        for (int wv = 0; wv < 4; ++wv) {
            t0 += red[wv][0]; t1 += red[wv][1];
            t2 += red[wv][2]; t3 += red[wv][3];
        }
        int ch0 = 2 * (n & 15);
        atomicAdd(stats + ch0,          t0);
        atomicAdd(stats + ch0 + 1,      t1);
        atomicAdd(stats + 32 + ch0,     t2);
        atomicAdd(stats + 32 + ch0 + 1, t3);
    }
}

// ---------------------------------------------------------------------------
// K4: fold BN + 1/128 scale into per-channel affine.
// ---------------------------------------------------------------------------
__global__ void finalize_kernel(const float* __restrict__ stats,
                                const float* __restrict__ gamma,
                                const float* __restrict__ beta,
                                float* __restrict__ AB) {
    int ch = threadIdx.x;
    if (ch < 2 * IC) {
        const float invN = 1.f / (float)BN_N;
        float mean = stats[ch] * invN;
        float var  = stats[32 + ch] * invN - mean * mean;
        float rs   = rsqrtf(var + BN_EPS);
        float a    = gamma[ch] * rs;
        AB[ch]      = a * (1.f / 128.f);
        AB[32 + ch] = (beta[ch] - a * mean) * (1.f / 128.f);
    }
}

// ---------------------------------------------------------------------------
// masked tap setup (unpadded planes; FIRST-step deform reads only)
// ---------------------------------------------------------------------------
__device__ __forceinline__ void tap_setup(float py, float px,
                                          int* o, float* wt) {
    float ffy = floorf(py), ffx = floorf(px);
    int y0 = (int)ffy, x0 = (int)ffx;
    float wy1 = py - ffy, wy0 = 1.f - wy1;
    float wx1 = px - ffx, wx0 = 1.f - wx1;
    bool vy0 = (unsigned)y0 < (unsigned)H, vy1 = (unsigned)(y0 + 1) < (unsigned)H;
    bool vx0 = (unsigned)x0 < (unsigned)W, vx1 = (unsigned)(x0 + 1) < (unsigned)W;
    int yc0 = min(max(y0, 0), H - 1), yc1 = min(max(y0 + 1, 0), H - 1);
    int xc0 = min(max(x0, 0), W - 1), xc1 = min(max(x0 + 1, 0), W - 1);
    o[0] = yc0 * W + xc0; o[1] = yc0 * W + xc1;
    o[2] = yc1 * W + xc0; o[3] = yc1 * W + xc1;
    wt[0] = (vy0 && vx0) ? wy0 * wx0 : 0.f;
    wt[1] = (vy0 && vx1) ? wy0 * wx1 : 0.f;
    wt[2] = (vy1 && vx0) ? wy1 * wx0 : 0.f;
    wt[3] = (vy1 && vx1) ? wy1 * wx1 : 0.f;
}

// ---------------------------------------------------------------------------
// fast tap setup for guard-padded planes
// ---------------------------------------------------------------------------
__device__ __forceinline__ void tap_fast(float py, float px,
                                         int& o, float* wt) {
    float pyc = fminf(fmaxf(py, -1.f), 256.f);
    float pxc = fminf(fmaxf(px, -1.f), 256.f);
    float fy = floorf(pyc), fx = floorf(pxc);
    int y0 = (int)fy, x0 = (int)fx;
    float wy1 = pyc - fy, wy0 = 1.f - wy1;
    float wx1 = pxc - fx, wx0 = 1.f - wx1;
    o = (y0 + 1) * PW + (x0 + 1);
    wt[0] = wy0 * wx0; wt[1] = wy0 * wx1;
    wt[2] = wy1 * wx0; wt[3] = wy1 * wx1;
}

// ---------------------------------------------------------------------------
// K5 (R12): channel-split warp step. R12 change: launch_bounds(256,8)
// (was 4) -> up to 32 waves/CU to hide the 3 dependent gather rounds.
// ---------------------------------------------------------------------------
template <bool FIRST, bool LAST>
__global__ __launch_bounds__(256, 8) void warp_step(
    const __half2* __restrict__ vinRaw, const __half2* __restrict__ vinPad,
    __half2* __restrict__ voutPad, const __half* __restrict__ f16p,
    const float* __restrict__ AB, __half* __restrict__ mvOut) {
    int blk  = blockIdx.x;            // 4096 = 128 fields x 32 bands
    int fld  = blk & 127;
    int band = blk >> 7;
    int c    = fld & 15;
    int tx   = threadIdx.x;
    const __half2* vinR = FIRST ? vinRaw + (size_t)fld * PLANE : nullptr;
    const __half2* vinP = FIRST ? nullptr : vinPad + (size_t)fld * PSZ;
    __half2* voutP = LAST ? nullptr : voutPad + (size_t)fld * PSZ;
    const __half* fp = f16p + (size_t)fld * PSZ;
    __half* mv = mvOut + (size_t)fld * PLANE;

    float a0 = 0.f, b0 = 0.f, a1 = 0.f, b1 = 0.f;
    if (FIRST) {
        a0 = AB[2 * c];     b0 = AB[32 + 2 * c];
        a1 = AB[2 * c + 1]; b1 = AB[32 + 2 * c + 1];
    }

#pragma unroll 4
    for (int r = 0; r < 8; ++r) {
        int h = band * 8 + r;
        int idx_raw = h * W + tx;
        int idx_pad = (h + 1) * PW + tx + 1;
        float ny, nx;
        if (FIRST) {
            float2 vc = __half22float2(vinR[idx_raw]);
            float fy = fmaf(a0, vc.x, b0);
            float fx = fmaf(a1, vc.y, b1);
            int om[4]; float wt[4];
            tap_setup((float)h + fy, (float)tx + fx, om, wt);
            float2 t0 = __half22float2(vinR[om[0]]);
            float2 t1 = __half22float2(vinR[om[1]]);
            float2 t2 = __half22float2(vinR[om[2]]);
            float2 t3 = __half22float2(vinR[om[3]]);
            float Sy = wt[0] * t0.x + wt[1] * t1.x + wt[2] * t2.x + wt[3] * t3.x;
            float Sx = wt[0] * t0.y + wt[1] * t1.y + wt[2] * t2.y + wt[3] * t3.y;
            float Ws = wt[0] + wt[1] + wt[2] + wt[3];
            ny = fy + fmaf(a0, Sy, b0 * Ws);
            nx = fx + fmaf(a1, Sx, b1 * Ws);
        } else {
            float2 vc = __half22float2(vinP[idx_pad]);
            float fy = vc.x, fx = vc.y;
            int ob; float wt[4];
            tap_fast((float)h + fy, (float)tx + fx, ob, wt);
            union { float2 f2; __half2 hh[2]; } top, bot;
            top.f2 = *reinterpret_cast<const float2*>(vinP + ob);
            bot.f2 = *reinterpret_cast<const float2*>(vinP + ob + PW);
            float2 t0 = __half22float2(top.hh[0]);
            float2 t1 = __half22float2(top.hh[1]);
            float2 t2 = __half22float2(bot.hh[0]);
            float2 t3 = __half22float2(bot.hh[1]);
            ny = fy + wt[0] * t0.x + wt[1] * t1.x + wt[2] * t2.x + wt[3] * t3.x;
            nx = fx + wt[0] * t0.y + wt[1] * t1.y + wt[2] * t2.y + wt[3] * t3.y;
        }
        if (!LAST)
            voutP[idx_pad] = __float22half2_rn(make_float2(ny, nx));
        int pb; float pw[4];
        tap_fast((float)h + ny, (float)tx + nx, pb, pw);
        union { float f; __half2 h2; } r0u, r1u;
        r0u.f = *reinterpret_cast<const float*>(fp + pb);
        r1u.f = *reinterpret_cast<const float*>(fp + pb + PW);
        float2 g0 = __half22float2(r0u.h2);
        float2 g1 = __half22float2(r1u.h2);
        float m = pw[0] * g0.x + pw[1] * g0.y + pw[2] * g1.x + pw[3] * g1.y;
        mv[idx_raw] = __float2half(m);
    }
}

// ---------------------------------------------------------------------------
// K6 (R12): deferred fuse mix v4 = v3 + '#pragma unroll 2' on s so the
// 16-load batch of step s+1 issues while step s's 256 FMAs execute
// (software pipelining; v3's unroll 1 serialized load-batch -> FMA-block).
// ---------------------------------------------------------------------------
__global__ __launch_bounds__(256) void mix_kernel(
    const __half* __restrict__ mvs,   // [6][NFIELDS][PLANE]
    const __half* __restrict__ mv6,   // [NFIELDS][PLANE] (bufRaw alias)
    const float* __restrict__ fw, const float* __restrict__ fb,
    float* __restrict__ out) {
    int blk = blockIdx.x;             // 2048 = 8 b x 256 h
    int b   = blk >> 8;
    int h   = blk & 255;
    int tx  = threadIdx.x;
    int idx = h * W + tx;

    float acc[IC];
#pragma unroll
    for (int o = 0; o < IC; ++o) acc[o] = fb[o];

#pragma unroll 2
    for (int s = 0; s < NSTEPS; ++s) {
        const __half* base = (s < NSTEPS - 1)
            ? mvs + (size_t)s * NFIELDS * PLANE : mv6;
        const __half* pbm = base + (size_t)b * IC * PLANE + idx;
        __half m[IC];
#pragma unroll
        for (int c = 0; c < IC; ++c)
            m[c] = pbm[(size_t)c * PLANE];
        const float* fws = fw + s;
#pragma unroll
        for (int c = 0; c < IC; ++c) {
            float mf = __half2float(m[c]);
#pragma unroll
            for (int o = 0; o < IC; ++o)
                acc[o] = fmaf(fws[(o * IC + c) * NSTEPS], mf, acc[o]);
        }
    }

#pragma unroll
    for (int o = 0; o < IC; ++o)
        out[(size_t)(b * IC + o) * PLANE + idx] = acc[o];
}

// ---------------------------------------------------------------------------
extern "C" void kernel_launch(void* const* d_in, const int* in_sizes, int n_in,
                              void* d_out, int out_size, void* d_ws,
                              size_t ws_size, hipStream_t stream) {
    const float* f      = (const float*)d_in[0];
    const float* vec_w  = (const float*)d_in[1];
    const float* vec_b  = (const float*)d_in[2];
    const float* gamma  = (const float*)d_in[3];
    const float* beta   = (const float*)d_in[4];
    const float* fuse_w = (const float*)d_in[5];
    const float* fuse_b = (const float*)d_in[6];
    float* out = (float*)d_out;

    // ws layout (bytes):
    //   bufRaw: 33.55 MB (conv out; mv6 alias after s=0)
    //   bufA: 34.61  bufB: 34.61  f16p: 17.31
    //   small: 16 KB (wTh, stats, AB)
    //   mvs: 6 x NFIELDS x PLANE half = 100.66 MB
    //   total ~220.8 MB (R9/R11 ran this exact footprint)
    char* ws = (char*)d_ws;
    const size_t rawB   = (size_t)NFIELDS * PLANE * sizeof(__half2);
    const size_t padB2  = (size_t)NFIELDS * PSZ * sizeof(__half2);
    const size_t padB1  = (size_t)NFIELDS * PSZ * sizeof(__half);
    const size_t smallB = 16384;
    __half2* bufRaw = (__half2*)ws;
    __half2* bufA   = (__half2*)(ws + rawB);
    __half2* bufB   = (__half2*)(ws + rawB + padB2);
    __half*  f16p   = (__half*)(ws + rawB + 2 * padB2);
    char*    smallp = ws + rawB + 2 * padB2 + padB1;
    __half2* wTh    = (__half2*)smallp;                       // 9216 B
    float*   stats  = (float*)(smallp + 10240);               // 256 B
    float*   AB     = (float*)(smallp + 10240 + 256);         // 256 B
    __half*  mvs    = (__half*)(smallp + smallB);

    hipMemsetAsync(stats, 0, 64 * sizeof(float), stream);
    transpose_w_kernel<<<1, 512, 0, stream>>>(vec_w, wTh);
    guard_zero_kernel<<<NFIELDS, 256, 0, stream>>>(
        (unsigned*)bufA, (unsigned*)bufB, (unsigned short*)f16p);
    dup_kernel<<<NFIELDS * 8, 256, 0, stream>>>(f, f16p);
    conv_kernel<<<2048, 256, 0, stream>>>(f, wTh, vec_b, bufRaw);
    stats_kernel<<<NFIELDS * 16, 256, 0, stream>>>(bufRaw, stats);
    finalize_kernel<<<1, 64, 0, stream>>>(stats, gamma, beta, AB);

    // s=0: bufRaw -> bufA; s odd: bufA -> bufB; s even>0: bufB -> bufA
    for (int s = 0; s < NSTEPS; ++s) {
        const __half2* vinPad = (s & 1) ? bufA : bufB;
        __half2*       voutP  = (s & 1) ? bufB : bufA;
        __half* mvP = (s < NSTEPS - 1) ? mvs + (size_t)s * NFIELDS * PLANE
                                       : (__half*)bufRaw;  // alias, safe after s=0
        if (s == 0)
            warp_step<true, false><<<4096, 256, 0, stream>>>(
                bufRaw, (const __half2*)nullptr, bufA, f16p, AB, mvP);
        else if (s < NSTEPS - 1)
            warp_step<false, false><<<4096, 256, 0, stream>>>(
                (const __half2*)nullptr, vinPad, voutP, f16p, AB, mvP);
        else
            warp_step<false, true><<<4096, 256, 0, stream>>>(
                (const __half2*)nullptr, vinPad, (__half2*)nullptr, f16p,
                AB, mvP);
    }
    mix_kernel<<<2048, 256, 0, stream>>>(
        mvs, (const __half*)bufRaw, fuse_w, fuse_b, out);
}